// Round 13
// baseline (239.729 us; speedup 1.0000x reference)
//
#include <hip/hip_runtime.h>
#include <stdint.h>

#define DD 128
#define NJ 25000
#define NI 12500
#define OVCAP 16384  // overflow-list capacity per layer (pairs)

__device__ __forceinline__ uint32_t rotl32(uint32_t v, int n) {
  return (v << n) | (v >> (32 - n));
}

// JAX threefry2x32, key=(0,1). Core KAT-verified vs Random123.
__device__ __forceinline__ void threefry_0_1(uint32_t& x0, uint32_t& x1) {
  const uint32_t ks0 = 0u, ks1 = 1u, ks2 = 0x1BD11BDBu;
  x0 += ks0; x1 += ks1;
#define TF_R4(a,b,c,d)                                  \
  x0 += x1; x1 = rotl32(x1,(a)); x1 ^= x0;              \
  x0 += x1; x1 = rotl32(x1,(b)); x1 ^= x0;              \
  x0 += x1; x1 = rotl32(x1,(c)); x1 ^= x0;              \
  x0 += x1; x1 = rotl32(x1,(d)); x1 ^= x0;
  TF_R4(13,15,26,6)   x0 += ks1; x1 += ks2 + 1u;
  TF_R4(17,29,16,24)  x0 += ks2; x1 += ks0 + 2u;
  TF_R4(13,15,26,6)   x0 += ks0; x1 += ks1 + 3u;
  TF_R4(17,29,16,24)  x0 += ks1; x1 += ks2 + 4u;
  TF_R4(13,15,26,6)   x0 += ks2; x1 += ks0 + 5u;
#undef TF_R4
}

// MASK IDENTIFIED (R16 sweep, unique match v5): partitionable threefry,
// ctr = (0, f), 32-bit draw = o0 ^ o1; keep <=> bit31(o0 ^ o1) == 0.
__device__ __forceinline__ bool dropout_keep(uint32_t f) {
  uint32_t x0 = 0u, x1 = f;
  threefry_0_1(x0, x1);
  return ((x0 ^ x1) >> 31) == 0u;
}

__device__ __forceinline__ float4 ld4(const float* p) {
  return *(const float4*)p;
}

#define ACC4(acc, v) \
  acc.x += v.x; acc.y += v.y; acc.z += v.z; acc.w += v.w;

// fp32 -> bf16 with round-to-nearest-even (inputs are finite).
__device__ __forceinline__ unsigned short f2bf(float f) {
  uint32_t u = __float_as_uint(f);
  u += 0x7FFFu + ((u >> 16) & 1u);
  return (unsigned short)(u >> 16);
}

// Unpack 8 bf16 (uint4) -> two float4, accumulate.
__device__ __forceinline__ void accbf8(const uint4& w, float4& lo, float4& hi) {
  lo.x += __uint_as_float(w.x << 16);
  lo.y += __uint_as_float(w.x & 0xFFFF0000u);
  lo.z += __uint_as_float(w.y << 16);
  lo.w += __uint_as_float(w.y & 0xFFFF0000u);
  hi.x += __uint_as_float(w.z << 16);
  hi.y += __uint_as_float(w.z & 0xFFFF0000u);
  hi.z += __uint_as_float(w.w << 16);
  hi.w += __uint_as_float(w.w & 0xFFFF0000u);
}

// Per-block inline int64-as-int32-pairs detect (odd words zero; L2-hit).
__device__ __forceinline__ int detect_flag_block(const int* __restrict__ w,
                                                 int* sf) {
  if (threadIdx.x == 0) {
    int is64 = 1;
    for (int e = 0; e < 16; ++e)
      if (w[2 * e + 1] != 0) is64 = 0;
    *sf = is64;
  }
  __syncthreads();
  return *sf;
}

// One-pass padded-bucket CSR build + weight prep + (optional) bf16 mirror.
//   blocks 0..255              : weight prep for BOTH layers
//   blocks 256..256+convB-1    : feat -> featb bf16 conversion (8 elems/thr)
//   blocks 256+convB..         : edge pass (bucket or overflow)
__global__ void setup_bucket(const float* __restrict__ Wl1,
                             const float* __restrict__ Wr1,
                             float* __restrict__ WT1,
                             const float* __restrict__ Wl2,
                             const float* __restrict__ Wr2,
                             float* __restrict__ WT2,
                             const int* __restrict__ adj1,
                             const int* __restrict__ adj2,
                             int* __restrict__ cnt1, int* __restrict__ cnt2,
                             int* __restrict__ ovCnt,
                             int* __restrict__ ovList1,
                             int* __restrict__ ovList2,
                             int* __restrict__ bucket1,
                             int* __restrict__ bucket2,
                             const float* __restrict__ feat,
                             unsigned short* __restrict__ featb,
                             int nConv, int convB,
                             int nE1, int nE2, int CAP) {
  const int b = blockIdx.x;
  if (b < 256) {
    int t = b * 256 + threadIdx.x;  // exactly covers 2*DD*256 = 65536
    int which = t >= DD * 256;
    int idx = which ? t - DD * 256 : t;
    const float* Wl = which ? Wl2 : Wl1;
    const float* Wr = which ? Wr2 : Wr1;
    float* WTp = which ? WT2 : WT1;
    int c = idx >> 8;
    int k = idx & 255;
    float v = (k < DD) ? Wl[c * DD + k] : Wr[c * DD + (k - DD)];
    WTp[(k >> 2) * (DD * 4) + c * 4 + (k & 3)] = v;
    return;
  }
  if (b < 256 + convB) {
    int i = (b - 256) * 2048 + threadIdx.x * 8;
    if (i < nConv) {
      float4 f0 = ld4(feat + i);
      float4 f1 = ld4(feat + i + 4);
      uint4 o;
      o.x = (uint32_t)f2bf(f0.x) | ((uint32_t)f2bf(f0.y) << 16);
      o.y = (uint32_t)f2bf(f0.z) | ((uint32_t)f2bf(f0.w) << 16);
      o.z = (uint32_t)f2bf(f1.x) | ((uint32_t)f2bf(f1.y) << 16);
      o.w = (uint32_t)f2bf(f1.z) | ((uint32_t)f2bf(f1.w) << 16);
      *(uint4*)(featb + i) = o;  // 16B aligned (i % 8 == 0)
    }
    return;
  }
  __shared__ int sf;
  const int f = detect_flag_block(adj1, &sf);
  int t = (b - 256 - convB) * 256 + threadIdx.x;
  if (t < nE1) {
    int s, d;
    if (f) {
      s = adj1[2 * t];
      d = adj1[2 * nE1 + 2 * t];
    } else {
      s = adj1[t];
      d = adj1[nE1 + t];
    }
    if (d < NJ) {
      int pos = atomicAdd(&cnt1[d], 1);
      if (pos < CAP) {
        bucket1[(size_t)d * CAP + pos] = s;
      } else {
        int op = atomicAdd(&ovCnt[0], 1);
        if (op < OVCAP) { ovList1[2 * op] = d; ovList1[2 * op + 1] = s; }
      }
    }
  } else if (t < nE1 + nE2) {
    int e = t - nE1;
    int s, d;
    if (f) {
      s = adj2[2 * e];
      d = adj2[2 * nE2 + 2 * e];
    } else {
      s = adj2[e];
      d = adj2[nE2 + e];
    }
    if (d < NI) {
      int pos = atomicAdd(&cnt2[d], 1);
      if (pos < CAP) {
        bucket2[(size_t)d * CAP + pos] = s;
      } else {
        int op = atomicAdd(&ovCnt[1], 1);
        if (op < OVCAP) { ovList2[2 * op] = d; ovList2[2 * op + 1] = s; }
      }
    }
  }
}

// Fused gather + dense, 256 threads, ROWS=32 (layer1) / 16 (layer2).
// R13 (SRCBF path): PAIRED-NEIGHBOR gather. A bf16 row is 256 B = 16 lanes
// x 16 B, so a 32-lane team loads TWO neighbor rows per VMEM instruction
// (lanes 0-15: even-indexed neighbor, 16-31: odd). 8 paired loads in
// flight = 16 neighbors per latency-batch -> deg<=16 rows (~92%) gather in
// ONE latency step (was 2); VMEM instruction count halved. Halves combined
// with 8 shfl_xor(16); half-1 lanes handle the xin slice.
// Dense: thread owns ROWS/8 rows x 4 cols; As reads are wave-uniform.
// LAYER==1: relu + dropout epilogue.
template <int ROWS, int LAYER, bool SRCBF, bool XINBF, bool OUTBF>
__global__ __launch_bounds__(256) void dense_kernel(
    const void* __restrict__ xsrc, const int* __restrict__ bucket,
    const int* __restrict__ cnt, const int* __restrict__ ovCnt,
    const int* __restrict__ ovList, const void* __restrict__ xin,
    const float* __restrict__ WTp, const float* __restrict__ bias,
    void* __restrict__ out, int M, int CAP) {
  __shared__ float As[ROWS * 256];
  const int tid = threadIdx.x;
  const int rowBase = blockIdx.x * ROWS;
  constexpr int RPT = ROWS / 8;  // rows per gather-team == rows per thread

  if constexpr (SRCBF) {
    // ---- paired-neighbor bf16 gather ----
    const int team = tid >> 5;
    const int lane = tid & 31;
    const int half = lane >> 4;  // 0: even neighbors, 1: odd neighbors
    const int sub = lane & 15;   // 8-elem (16 B) slot within the row
    const unsigned short* xb = (const unsigned short*)xsrc;
#pragma unroll
    for (int rr = 0; rr < RPT; ++rr) {
      const int r = team * RPT + rr;
      int rg = rowBase + r;
      if (rg >= M) rg = M - 1;  // clamped read; stores guarded below
      const int deg = cnt[rg];
      const int nb = (deg < CAP) ? deg : CAP;
      const int* bk = bucket + (size_t)rg * CAP;  // 16B-aligned (CAP%8==0)
      const int4* bi4 = (const int4*)bk;
      float4 aLo = {0.f, 0.f, 0.f, 0.f}, aHi = aLo;
      int p = 0;
      for (; p + 15 < nb; p += 16) {  // 16 neighbors per latency-batch
        int4 q0 = bi4[(p >> 2) + 0];
        int4 q1 = bi4[(p >> 2) + 1];
        int4 q2 = bi4[(p >> 2) + 2];
        int4 q3 = bi4[(p >> 2) + 3];
        int s0 = half ? q0.y : q0.x, s1 = half ? q0.w : q0.z;
        int s2 = half ? q1.y : q1.x, s3 = half ? q1.w : q1.z;
        int s4 = half ? q2.y : q2.x, s5 = half ? q2.w : q2.z;
        int s6 = half ? q3.y : q3.x, s7 = half ? q3.w : q3.z;
        uint4 w0 = *(const uint4*)(xb + (size_t)s0 * DD + sub * 8);
        uint4 w1 = *(const uint4*)(xb + (size_t)s1 * DD + sub * 8);
        uint4 w2 = *(const uint4*)(xb + (size_t)s2 * DD + sub * 8);
        uint4 w3 = *(const uint4*)(xb + (size_t)s3 * DD + sub * 8);
        uint4 w4 = *(const uint4*)(xb + (size_t)s4 * DD + sub * 8);
        uint4 w5 = *(const uint4*)(xb + (size_t)s5 * DD + sub * 8);
        uint4 w6 = *(const uint4*)(xb + (size_t)s6 * DD + sub * 8);
        uint4 w7 = *(const uint4*)(xb + (size_t)s7 * DD + sub * 8);
        accbf8(w0, aLo, aHi); accbf8(w1, aLo, aHi);
        accbf8(w2, aLo, aHi); accbf8(w3, aLo, aHi);
        accbf8(w4, aLo, aHi); accbf8(w5, aLo, aHi);
        accbf8(w6, aLo, aHi); accbf8(w7, aLo, aHi);
      }
      for (; p + 1 < nb; p += 2) {  // paired tail
        int2 pr = *(const int2*)(bk + p);
        int s = half ? pr.y : pr.x;
        uint4 w = *(const uint4*)(xb + (size_t)s * DD + sub * 8);
        accbf8(w, aLo, aHi);
      }
      if (p < nb && half == 0) {  // odd-deg last neighbor
        uint4 w = *(const uint4*)(xb + (size_t)bk[p] * DD + sub * 8);
        accbf8(w, aLo, aHi);
      }
      if (deg > CAP && half == 0) {  // rare overflow scan
        int ovc = *ovCnt;
        if (ovc > OVCAP) ovc = OVCAP;
        for (int o = 0; o < ovc; ++o) {
          if (ovList[2 * o] == rg) {
            uint4 w =
                *(const uint4*)(xb + (size_t)ovList[2 * o + 1] * DD + sub * 8);
            accbf8(w, aLo, aHi);
          }
        }
      }
      // combine even/odd halves (lane ^ 16); both halves end with the sum
      aLo.x += __shfl_xor(aLo.x, 16);
      aLo.y += __shfl_xor(aLo.y, 16);
      aLo.z += __shfl_xor(aLo.z, 16);
      aLo.w += __shfl_xor(aLo.w, 16);
      aHi.x += __shfl_xor(aHi.x, 16);
      aHi.y += __shfl_xor(aHi.y, 16);
      aHi.z += __shfl_xor(aHi.z, 16);
      aHi.w += __shfl_xor(aHi.w, 16);
      float rdeg = 1.0f / fmaxf((float)deg, 1.0f);
      aLo.x *= rdeg; aLo.y *= rdeg; aLo.z *= rdeg; aLo.w *= rdeg;
      aHi.x *= rdeg; aHi.y *= rdeg; aHi.z *= rdeg; aHi.w *= rdeg;
      if (half == 0) {
        *(float4*)(As + r * 256 + sub * 8) = aLo;
        *(float4*)(As + r * 256 + sub * 8 + 4) = aHi;
      } else {
        float4 x0, x1v;
        if constexpr (XINBF) {
          const unsigned short* xi = (const unsigned short*)xin;
          uint4 w = *(const uint4*)(xi + (size_t)rg * DD + sub * 8);
          float4 z = {0.f, 0.f, 0.f, 0.f};
          x0 = z; x1v = z;
          accbf8(w, x0, x1v);
        } else {
          const float* xi = (const float*)xin;
          x0 = ld4(xi + (size_t)rg * DD + sub * 8);
          x1v = ld4(xi + (size_t)rg * DD + sub * 8 + 4);
        }
        *(float4*)(As + r * 256 + DD + sub * 8) = x0;
        *(float4*)(As + r * 256 + DD + sub * 8 + 4) = x1v;
      }
    }
  } else {
    // ---- proven R7 fp32 gather ----
    const int team = tid >> 5;
    const int l4 = (tid & 31) * 4;
    const float* xf = (const float*)xsrc;
#pragma unroll
    for (int rr = 0; rr < RPT; ++rr) {
      const int r = team * RPT + rr;
      int rg = rowBase + r;
      if (rg >= M) rg = M - 1;
      const int deg = cnt[rg];
      const int nb = (deg < CAP) ? deg : CAP;
      const int* bk = bucket + (size_t)rg * CAP;
      const int4* bi4 = (const int4*)bk;
      float4 a0 = {0.f, 0.f, 0.f, 0.f}, a1 = a0, a2 = a0, a3 = a0;
      int e = 0;
      for (; e + 7 < nb; e += 8) {
        int4 i0 = bi4[e >> 2], i1 = bi4[(e >> 2) + 1];
        float4 v0 = ld4(xf + (size_t)i0.x * DD + l4);
        float4 v1 = ld4(xf + (size_t)i0.y * DD + l4);
        float4 v2 = ld4(xf + (size_t)i0.z * DD + l4);
        float4 v3 = ld4(xf + (size_t)i0.w * DD + l4);
        float4 v4 = ld4(xf + (size_t)i1.x * DD + l4);
        float4 v5 = ld4(xf + (size_t)i1.y * DD + l4);
        float4 v6 = ld4(xf + (size_t)i1.z * DD + l4);
        float4 v7 = ld4(xf + (size_t)i1.w * DD + l4);
        ACC4(a0, v0) ACC4(a1, v1) ACC4(a2, v2) ACC4(a3, v3)
        ACC4(a0, v4) ACC4(a1, v5) ACC4(a2, v6) ACC4(a3, v7)
      }
      for (; e < nb; ++e) {
        float4 v = ld4(xf + (size_t)bk[e] * DD + l4);
        ACC4(a0, v)
      }
      if (deg > CAP) {
        int ovc = *ovCnt;
        if (ovc > OVCAP) ovc = OVCAP;
        for (int o = 0; o < ovc; ++o) {
          if (ovList[2 * o] == rg) {
            float4 v = ld4(xf + (size_t)ovList[2 * o + 1] * DD + l4);
            ACC4(a0, v)
          }
        }
      }
      a0.x += a1.x + a2.x + a3.x;
      a0.y += a1.y + a2.y + a3.y;
      a0.z += a1.z + a2.z + a3.z;
      a0.w += a1.w + a2.w + a3.w;
      float rdeg = 1.0f / fmaxf((float)deg, 1.0f);
      a0.x *= rdeg; a0.y *= rdeg; a0.z *= rdeg; a0.w *= rdeg;
      *(float4*)(As + r * 256 + l4) = a0;
      *(float4*)(As + r * 256 + DD + l4) =
          ld4((const float*)xin + (size_t)rg * DD + l4);
    }
  }
  __syncthreads();

  // ---- dense phase: RPT rows x 4 cols per thread ----
  const int u = tid & 31;   // cols u, u+32, u+64, u+96
  const int g = tid >> 5;   // row group 0..7 (wave-uniform)
  const int r0 = g * RPT;
  float acc[RPT][4];
#pragma unroll
  for (int r = 0; r < RPT; ++r)
    acc[r][0] = acc[r][1] = acc[r][2] = acc[r][3] = 0.f;

#pragma unroll 8
  for (int k0 = 0; k0 < 256; k0 += 4) {
    const float* wbase = WTp + (k0 >> 2) * (DD * 4);
    float4 w0 = ld4(wbase + u * 4);
    float4 w1 = ld4(wbase + (u + 32) * 4);
    float4 w2 = ld4(wbase + (u + 64) * 4);
    float4 w3 = ld4(wbase + (u + 96) * 4);
#pragma unroll
    for (int r = 0; r < RPT; ++r) {
      float4 a = *(const float4*)(As + (r0 + r) * 256 + k0);
      acc[r][0] += a.x * w0.x + a.y * w0.y + a.z * w0.z + a.w * w0.w;
      acc[r][1] += a.x * w1.x + a.y * w1.y + a.z * w1.z + a.w * w1.w;
      acc[r][2] += a.x * w2.x + a.y * w2.y + a.z * w2.z + a.w * w2.w;
      acc[r][3] += a.x * w3.x + a.y * w3.y + a.z * w3.z + a.w * w3.w;
    }
  }

  float bb[4] = {bias[u], bias[u + 32], bias[u + 64], bias[u + 96]};
#pragma unroll
  for (int r = 0; r < RPT; ++r) {
    int rg = rowBase + r0 + r;
    if (rg >= M) continue;
#pragma unroll
    for (int i = 0; i < 4; ++i) {
      int cc = u + 32 * i;
      float v = acc[r][i] + bb[i];
      if (LAYER == 1) {
        v = fmaxf(v, 0.0f);
        v = dropout_keep((uint32_t)rg * DD + (uint32_t)cc) ? v * 2.0f : 0.0f;
      }
      if constexpr (OUTBF) {
        ((unsigned short*)out)[(size_t)rg * DD + cc] = f2bf(v);
      } else {
        ((float*)out)[(size_t)rg * DD + cc] = v;
      }
    }
  }
}

extern "C" void kernel_launch(void* const* d_in, const int* in_sizes, int n_in,
                              void* d_out, int out_size, void* d_ws, size_t ws_size,
                              hipStream_t stream) {
  const float* feat = (const float*)d_in[0];   // fp32 (R4 NaN proof)
  const int* t_adj = (const int*)d_in[1];
  const int* n_adj = (const int*)d_in[2];
  const float* W1l = (const float*)d_in[5];
  const float* b1 = (const float*)d_in[6];
  const float* W1r = (const float*)d_in[7];
  const float* W2l = (const float*)d_in[8];
  const float* b2 = (const float*)d_in[9];
  const float* W2r = (const float*)d_in[10];

  // in_sizes[] counts ELEMENTS (proven: E1 = in_sizes[1]/2 since R0).
  const int E1 = in_sizes[1] / 2;
  const int E2 = in_sizes[2] / 2;
  const int N = in_sizes[0] / DD;  // 50000

  const long wsInts = (long)(ws_size / 4);
  const long featbInts = (long)N * DD / 2;    // bf16 mirror of feat (ints)
  const long x1bInts = (long)NJ * DD / 2;     // bf16 x1 (ints)
  const long fixedB =
      featbInts + x1bInts + 65536 + NJ + NI + 8 + 4L * OVCAP;
  int capB = (int)((wsInts - fixedB) / (NJ + NI)) & ~7;
  const bool useBf = capB >= 24;  // P(deg>24 | lambda=12) ~ 0.06%

  const int nTot = E1 + E2;
  const int edgeB = (nTot + 255) / 256;

  if (useBf) {
    // ---- bf16-gather layout ----
    int CAP = capB > 64 ? 64 : capB;
    char* p = (char*)d_ws;
    unsigned short* featb = (unsigned short*)p;      p += featbInts * 4;
    unsigned short* x1b = (unsigned short*)p;        p += x1bInts * 4;
    float* WT1 = (float*)p;                          p += 32768 * 4;
    float* WT2 = (float*)p;                          p += 32768 * 4;
    int* cnt1 = (int*)p;                             p += NJ * 4;
    int* cnt2 = (int*)p;                             p += NI * 4;
    int* ovCnt = (int*)p;                            p += 8 * 4;
    int* ovList1 = (int*)p;                          p += 2 * OVCAP * 4;
    int* ovList2 = (int*)p;                          p += 2 * OVCAP * 4;
    int* bucket1 = (int*)p;                          p += (size_t)NJ * CAP * 4;
    int* bucket2 = (int*)p;

    hipMemsetAsync(cnt1, 0, (size_t)(NJ + NI + 8) * sizeof(int), stream);

    const int nConv = N * DD;
    const int convB = (nConv + 2047) / 2048;
    setup_bucket<<<256 + convB + edgeB, 256, 0, stream>>>(
        W1l, W1r, WT1, W2l, W2r, WT2, t_adj, n_adj, cnt1, cnt2, ovCnt,
        ovList1, ovList2, bucket1, bucket2, feat, featb, nConv, convB, E1, E2,
        CAP);

    dense_kernel<32, 1, true, false, true>
        <<<(NJ + 31) / 32, 256, 0, stream>>>(featb, bucket1, cnt1, ovCnt + 0,
                                             ovList1, feat, WT1, b1, x1b, NJ,
                                             CAP);
    dense_kernel<16, 2, true, true, false>
        <<<(NI + 15) / 16, 256, 0, stream>>>(x1b, bucket2, cnt2, ovCnt + 1,
                                             ovList2, x1b, WT2, b2, d_out, NI,
                                             CAP);
  } else {
    // ---- proven R7 fp32 layout (fallback) ----
    float* ws = (float*)d_ws;
    float* x1 = ws;
    float* WT1 = x1 + 3200000;
    float* WT2 = WT1 + 32768;
    int* cnt1 = (int*)(WT2 + 32768);
    int* cnt2 = cnt1 + NJ;
    int* ovCnt = cnt2 + NI;
    int* ovList1 = ovCnt + 8;
    int* ovList2 = ovList1 + 2 * OVCAP;
    int* bucket1 = ovList2 + 2 * OVCAP;

    const long fixedInts =
        3200000L + 32768 + 32768 + NJ + NI + 8 + 4L * OVCAP;
    int CAP = (int)((wsInts - fixedInts) / (NJ + NI));
    if (CAP > 64) CAP = 64;
    if (CAP < 16) CAP = 16;
    CAP &= ~7;

    int* bucket2 = bucket1 + (size_t)NJ * CAP;

    hipMemsetAsync(cnt1, 0, (size_t)(NJ + NI + 8) * sizeof(int), stream);

    setup_bucket<<<256 + edgeB, 256, 0, stream>>>(
        W1l, W1r, WT1, W2l, W2r, WT2, t_adj, n_adj, cnt1, cnt2, ovCnt,
        ovList1, ovList2, bucket1, bucket2, feat, (unsigned short*)nullptr, 0,
        0, E1, E2, CAP);

    dense_kernel<32, 1, false, false, false>
        <<<(NJ + 31) / 32, 256, 0, stream>>>(feat, bucket1, cnt1, ovCnt + 0,
                                             ovList1, feat, WT1, b1, x1, NJ,
                                             CAP);
    dense_kernel<16, 2, false, false, false>
        <<<(NI + 15) / 16, 256, 0, stream>>>(x1, bucket2, cnt2, ovCnt + 1,
                                             ovList2, x1, WT2, b2, d_out, NI,
                                             CAP);
  }
}

// Round 14
// 233.671 us; speedup vs baseline: 1.0259x; 1.0259x over previous
//
#include <hip/hip_runtime.h>
#include <stdint.h>

#define DD 128
#define NJ 25000
#define NI 12500
#define OVCAP 16384  // overflow-list capacity per layer (pairs)

__device__ __forceinline__ uint32_t rotl32(uint32_t v, int n) {
  return (v << n) | (v >> (32 - n));
}

// JAX threefry2x32, key=(0,1). Core KAT-verified vs Random123.
__device__ __forceinline__ void threefry_0_1(uint32_t& x0, uint32_t& x1) {
  const uint32_t ks0 = 0u, ks1 = 1u, ks2 = 0x1BD11BDBu;
  x0 += ks0; x1 += ks1;
#define TF_R4(a,b,c,d)                                  \
  x0 += x1; x1 = rotl32(x1,(a)); x1 ^= x0;              \
  x0 += x1; x1 = rotl32(x1,(b)); x1 ^= x0;              \
  x0 += x1; x1 = rotl32(x1,(c)); x1 ^= x0;              \
  x0 += x1; x1 = rotl32(x1,(d)); x1 ^= x0;
  TF_R4(13,15,26,6)   x0 += ks1; x1 += ks2 + 1u;
  TF_R4(17,29,16,24)  x0 += ks2; x1 += ks0 + 2u;
  TF_R4(13,15,26,6)   x0 += ks0; x1 += ks1 + 3u;
  TF_R4(17,29,16,24)  x0 += ks1; x1 += ks2 + 4u;
  TF_R4(13,15,26,6)   x0 += ks2; x1 += ks0 + 5u;
#undef TF_R4
}

// MASK IDENTIFIED (R16 sweep, unique match v5): partitionable threefry,
// ctr = (0, f), 32-bit draw = o0 ^ o1; keep <=> bit31(o0 ^ o1) == 0.
__device__ __forceinline__ bool dropout_keep(uint32_t f) {
  uint32_t x0 = 0u, x1 = f;
  threefry_0_1(x0, x1);
  return ((x0 ^ x1) >> 31) == 0u;
}

__device__ __forceinline__ float4 ld4(const float* p) {
  return *(const float4*)p;
}

#define ACC4(acc, v) \
  acc.x += v.x; acc.y += v.y; acc.z += v.z; acc.w += v.w;

// Per-block inline int64-as-int32-pairs detect (odd words zero; L2-hit).
__device__ __forceinline__ int detect_flag_block(const int* __restrict__ w,
                                                 int* sf) {
  if (threadIdx.x == 0) {
    int is64 = 1;
    for (int e = 0; e < 16; ++e)
      if (w[2 * e + 1] != 0) is64 = 0;
    *sf = is64;
  }
  __syncthreads();
  return *sf;
}

__device__ __forceinline__ void bucket_insert(int d, int s, int dstLimit,
                                              int* __restrict__ cnt,
                                              int* __restrict__ bucket,
                                              int* __restrict__ ovCnt,
                                              int* __restrict__ ovList,
                                              int CAP) {
  if (d < dstLimit) {
    int pos = atomicAdd(&cnt[d], 1);
    if (pos < CAP) {
      bucket[(size_t)d * CAP + pos] = s;
    } else {
      int op = atomicAdd(ovCnt, 1);
      if (op < OVCAP) { ovList[2 * op] = d; ovList[2 * op + 1] = s; }
    }
  }
}

// One-pass padded-bucket CSR build fused with weight prep.
//   blocks 0..255 : weight prep for BOTH layers
//   blocks 256..  : edge pass, TWO edges per thread via int4/int2 loads
//                   (full-width coalesced reads; 2 independent atomic
//                   chains per thread). nE1 is even so pairs never
//                   straddle the list boundary.
// cnt arrays pre-zeroed by memsetAsync. Overflow (deg>CAP) edges go to a
// compact (d,s) list; gather handles them exactly (Poisson tail, rare).
// WTp[(k>>2)*512 + c*4 + (k&3)] = Wcat[c][k]; Wcat = [W_l | W_r] along k.
__global__ void setup_bucket(const float* __restrict__ Wl1,
                             const float* __restrict__ Wr1,
                             float* __restrict__ WT1,
                             const float* __restrict__ Wl2,
                             const float* __restrict__ Wr2,
                             float* __restrict__ WT2,
                             const int* __restrict__ adj1,
                             const int* __restrict__ adj2,
                             int* __restrict__ cnt1, int* __restrict__ cnt2,
                             int* __restrict__ ovCnt,
                             int* __restrict__ ovList1,
                             int* __restrict__ ovList2,
                             int* __restrict__ bucket1,
                             int* __restrict__ bucket2,
                             int nE1, int nE2, int CAP) {
  const int b = blockIdx.x;
  if (b < 256) {
    int t = b * 256 + threadIdx.x;  // exactly covers 2*DD*256 = 65536
    int which = t >= DD * 256;
    int idx = which ? t - DD * 256 : t;
    const float* Wl = which ? Wl2 : Wl1;
    const float* Wr = which ? Wr2 : Wr1;
    float* WTp = which ? WT2 : WT1;
    int c = idx >> 8;
    int k = idx & 255;
    float v = (k < DD) ? Wl[c * DD + k] : Wr[c * DD + (k - DD)];
    WTp[(k >> 2) * (DD * 4) + c * 4 + (k & 3)] = v;
    return;
  }
  __shared__ int sf;
  const int f = detect_flag_block(adj1, &sf);
  const int u = (b - 256) * 256 + threadIdx.x;  // edge-PAIR index
  const int e0 = 2 * u;
  if (e0 < nE1) {
    int s0, d0, s1, d1;
    int have2 = (e0 + 1 < nE1);
    if (f) {
      int4 ps = *(const int4*)(adj1 + 4 * u);            // {s0,hi,s1,hi}
      int4 pd = *(const int4*)(adj1 + 2 * nE1 + 4 * u);  // {d0,hi,d1,hi}
      s0 = ps.x; s1 = ps.z; d0 = pd.x; d1 = pd.z;
    } else {
      int2 ps = *(const int2*)(adj1 + 2 * u);
      int2 pd = *(const int2*)(adj1 + nE1 + 2 * u);
      s0 = ps.x; s1 = ps.y; d0 = pd.x; d1 = pd.y;
    }
    bucket_insert(d0, s0, NJ, cnt1, bucket1, ovCnt + 0, ovList1, CAP);
    if (have2)
      bucket_insert(d1, s1, NJ, cnt1, bucket1, ovCnt + 0, ovList1, CAP);
  } else if (e0 < nE1 + nE2) {
    const int v = u - nE1 / 2;  // pair index within list2 (nE1 even)
    const int g0 = 2 * v;
    int s0, d0, s1, d1;
    int have2 = (g0 + 1 < nE2);
    if (f) {
      int4 ps = *(const int4*)(adj2 + 4 * v);
      int4 pd = *(const int4*)(adj2 + 2 * nE2 + 4 * v);
      s0 = ps.x; s1 = ps.z; d0 = pd.x; d1 = pd.z;
    } else {
      int2 ps = *(const int2*)(adj2 + 2 * v);
      int2 pd = *(const int2*)(adj2 + nE2 + 2 * v);
      s0 = ps.x; s1 = ps.y; d0 = pd.x; d1 = pd.y;
    }
    bucket_insert(d0, s0, NI, cnt2, bucket2, ovCnt + 1, ovList2, CAP);
    if (have2)
      bucket_insert(d1, s1, NI, cnt2, bucket2, ovCnt + 1, ovList2, CAP);
  }
}

// Fused gather + dense, 256 threads (R7 config: 48 VGPR, best measured).
// ROWS=32 (layer1), 16 (layer2).
// Gather: 8 teams x 32 lanes, ROWS/8 rows per team, lane owns 16 B;
// int4 index loads, 8 feature loads in flight.
// Dense: thread owns ROWS/8 rows x 4 cols; As reads are wave-uniform.
// LAYER==1: relu + dropout epilogue.
template <int ROWS, int LAYER>
__global__ __launch_bounds__(256) void dense_kernel(
    const float* __restrict__ xsrc, const int* __restrict__ bucket,
    const int* __restrict__ cnt, const int* __restrict__ ovCnt,
    const int* __restrict__ ovList, const float* __restrict__ xin,
    const float* __restrict__ WTp, const float* __restrict__ bias,
    float* __restrict__ out, int M, int CAP) {
  __shared__ float As[ROWS * 256];
  const int tid = threadIdx.x;
  const int rowBase = blockIdx.x * ROWS;
  constexpr int RPT = ROWS / 8;  // rows per gather-team == rows per thread

  // ---- gather phase ----
  {
    const int team = tid >> 5;      // 0..7
    const int l4 = (tid & 31) * 4;  // float4 slot within row
#pragma unroll
    for (int rr = 0; rr < RPT; ++rr) {
      const int r = team * RPT + rr;
      int rg = rowBase + r;
      if (rg >= M) rg = M - 1;  // clamped read; stores guarded below
      const int deg = cnt[rg];
      const int nb = (deg < CAP) ? deg : CAP;
      const int* bk = bucket + (size_t)rg * CAP;  // 16B-aligned (CAP%8==0)
      const int4* bi4 = (const int4*)bk;
      float4 a0 = {0.f, 0.f, 0.f, 0.f}, a1 = a0, a2 = a0, a3 = a0;
      int e = 0;
      for (; e + 7 < nb; e += 8) {
        int4 i0 = bi4[e >> 2], i1 = bi4[(e >> 2) + 1];
        float4 v0 = ld4(xsrc + (size_t)i0.x * DD + l4);
        float4 v1 = ld4(xsrc + (size_t)i0.y * DD + l4);
        float4 v2 = ld4(xsrc + (size_t)i0.z * DD + l4);
        float4 v3 = ld4(xsrc + (size_t)i0.w * DD + l4);
        float4 v4 = ld4(xsrc + (size_t)i1.x * DD + l4);
        float4 v5 = ld4(xsrc + (size_t)i1.y * DD + l4);
        float4 v6 = ld4(xsrc + (size_t)i1.z * DD + l4);
        float4 v7 = ld4(xsrc + (size_t)i1.w * DD + l4);
        ACC4(a0, v0) ACC4(a1, v1) ACC4(a2, v2) ACC4(a3, v3)
        ACC4(a0, v4) ACC4(a1, v5) ACC4(a2, v6) ACC4(a3, v7)
      }
      for (; e < nb; ++e) {
        float4 v = ld4(xsrc + (size_t)bk[e] * DD + l4);
        ACC4(a0, v)
      }
      if (deg > CAP) {  // rare: scan compact overflow list for this row
        int ovc = *ovCnt;
        if (ovc > OVCAP) ovc = OVCAP;
        for (int o = 0; o < ovc; ++o) {
          if (ovList[2 * o] == rg) {
            float4 v = ld4(xsrc + (size_t)ovList[2 * o + 1] * DD + l4);
            ACC4(a0, v)
          }
        }
      }
      a0.x += a1.x + a2.x + a3.x;
      a0.y += a1.y + a2.y + a3.y;
      a0.z += a1.z + a2.z + a3.z;
      a0.w += a1.w + a2.w + a3.w;
      float rdeg = 1.0f / fmaxf((float)deg, 1.0f);
      a0.x *= rdeg; a0.y *= rdeg; a0.z *= rdeg; a0.w *= rdeg;
      *(float4*)(As + r * 256 + l4) = a0;
      *(float4*)(As + r * 256 + DD + l4) = ld4(xin + (size_t)rg * DD + l4);
    }
  }
  __syncthreads();

  // ---- dense phase: RPT rows x 4 cols per thread ----
  const int u = tid & 31;   // cols u, u+32, u+64, u+96
  const int g = tid >> 5;   // row group 0..7 (wave-uniform)
  const int r0 = g * RPT;
  float acc[RPT][4];
#pragma unroll
  for (int r = 0; r < RPT; ++r)
    acc[r][0] = acc[r][1] = acc[r][2] = acc[r][3] = 0.f;

#pragma unroll 8
  for (int k0 = 0; k0 < 256; k0 += 4) {
    const float* wbase = WTp + (k0 >> 2) * (DD * 4);
    float4 w0 = ld4(wbase + u * 4);
    float4 w1 = ld4(wbase + (u + 32) * 4);
    float4 w2 = ld4(wbase + (u + 64) * 4);
    float4 w3 = ld4(wbase + (u + 96) * 4);
#pragma unroll
    for (int r = 0; r < RPT; ++r) {
      float4 a = *(const float4*)(As + (r0 + r) * 256 + k0);
      acc[r][0] += a.x * w0.x + a.y * w0.y + a.z * w0.z + a.w * w0.w;
      acc[r][1] += a.x * w1.x + a.y * w1.y + a.z * w1.z + a.w * w1.w;
      acc[r][2] += a.x * w2.x + a.y * w2.y + a.z * w2.z + a.w * w2.w;
      acc[r][3] += a.x * w3.x + a.y * w3.y + a.z * w3.z + a.w * w3.w;
    }
  }

  float bb[4] = {bias[u], bias[u + 32], bias[u + 64], bias[u + 96]};
#pragma unroll
  for (int r = 0; r < RPT; ++r) {
    int rg = rowBase + r0 + r;
    if (rg >= M) continue;
#pragma unroll
    for (int i = 0; i < 4; ++i) {
      int cc = u + 32 * i;
      float v = acc[r][i] + bb[i];
      if (LAYER == 1) {
        v = fmaxf(v, 0.0f);
        v = dropout_keep((uint32_t)rg * DD + (uint32_t)cc) ? v * 2.0f : 0.0f;
      }
      out[(size_t)rg * DD + cc] = v;
    }
  }
}

extern "C" void kernel_launch(void* const* d_in, const int* in_sizes, int n_in,
                              void* d_out, int out_size, void* d_ws, size_t ws_size,
                              hipStream_t stream) {
  const float* feat = (const float*)d_in[0];   // fp32 (R4 NaN proof)
  const int* t_adj = (const int*)d_in[1];
  const int* n_adj = (const int*)d_in[2];
  const float* W1l = (const float*)d_in[5];
  const float* b1 = (const float*)d_in[6];
  const float* W1r = (const float*)d_in[7];
  const float* W2l = (const float*)d_in[8];
  const float* b2 = (const float*)d_in[9];
  const float* W2r = (const float*)d_in[10];

  // in_sizes[] counts ELEMENTS (proven: E1 = in_sizes[1]/2 since R0).
  const int E1 = in_sizes[1] / 2;
  const int E2 = in_sizes[2] / 2;

  // Workspace layout (proven R7 fp32 layout). CAP sized from ws_size.
  float* ws = (float*)d_ws;
  float* x1 = ws;                          // 3,200,000 f
  float* WT1 = x1 + 3200000;               //    32,768 f
  float* WT2 = WT1 + 32768;                //    32,768 f
  int* cnt1 = (int*)(WT2 + 32768);         //    NJ
  int* cnt2 = cnt1 + NJ;                   //    NI
  int* ovCnt = cnt2 + NI;                  //    8 (2 used)
  int* ovList1 = ovCnt + 8;                //    2*OVCAP
  int* ovList2 = ovList1 + 2 * OVCAP;      //    2*OVCAP
  int* bucket1 = ovList2 + 2 * OVCAP;      //    NJ*CAP

  const long wsInts = (long)(ws_size / 4);
  const long fixedInts = 3200000L + 32768 + 32768 + NJ + NI + 8 + 4L * OVCAP;
  int CAP = (int)((wsInts - fixedInts) / (NJ + NI));
  if (CAP > 64) CAP = 64;
  if (CAP < 16) CAP = 16;  // ws proven >= 19.6 MB by earlier rounds
  CAP &= ~7;               // multiple of 8: 16B-aligned bucket rows (int4)

  int* bucket2 = bucket1 + (size_t)NJ * CAP;  // NI*CAP

  // Zero cnt1, cnt2, ovCnt (contiguous): (NJ+NI+8) ints.
  hipMemsetAsync(cnt1, 0, (size_t)(NJ + NI + 8) * sizeof(int), stream);

  const int nTot = E1 + E2;
  const int pairB = (nTot / 2 + 255) / 256;  // 2 edges per thread
  setup_bucket<<<256 + pairB, 256, 0, stream>>>(
      W1l, W1r, WT1, W2l, W2r, WT2, t_adj, n_adj, cnt1, cnt2, ovCnt, ovList1,
      ovList2, bucket1, bucket2, E1, E2, CAP);

  dense_kernel<32, 1><<<(NJ + 31) / 32, 256, 0, stream>>>(
      feat, bucket1, cnt1, ovCnt + 0, ovList1, feat, WT1, b1, x1, NJ, CAP);
  dense_kernel<16, 2><<<(NI + 15) / 16, 256, 0, stream>>>(
      x1, bucket2, cnt2, ovCnt + 1, ovList2, x1, WT2, b2, (float*)d_out, NI,
      CAP);
}